// Round 7
// baseline (214.793 us; speedup 1.0000x reference)
//
#include <hip/hip_runtime.h>
#include <math.h>

#define NNODES 51200
#define BGRAPHS 128
#define NPG 400
#define NEDGES 819200
#define EPG 6400    // edges per graph
#define SLP 7680    // padded src-list stride per graph (u16 entries, 1920 groups)

// ---------------- CSR build (padded 4-edge groups) ----------------
__global__ __launch_bounds__(512) void csr_build_kernel(
    const int* __restrict__ src, const int* __restrict__ dst,
    unsigned short* __restrict__ slg, int* __restrict__ gsg, int* __restrict__ gcg,
    float* __restrict__ nmask, float* __restrict__ dinv, float* __restrict__ sc,
    float* __restrict__ hp) {
    __shared__ int deg[NPG];
    __shared__ int incl[512];
    __shared__ int gs[NPG];
    __shared__ int cur[NPG];
    const int g = blockIdx.x, t = threadIdx.x;
    for (int i = t; i < NPG; i += 512) deg[i] = 0;
    if (t < 128) hp[g * 128 + t] = 0.0f;   // zero-init for gemm4's fused maxpool
    __syncthreads();
    for (int e = t; e < EPG; e += 512)
        atomicAdd(&deg[dst[g * EPG + e] - g * NPG], 1);
    __syncthreads();
    const int d = (t < NPG) ? deg[t] : 0;
    const int p = (d + 3) >> 2;   // padded group count
    incl[t] = p;
    __syncthreads();
    for (int off = 1; off < 512; off <<= 1) {
        int add = (t >= off) ? incl[t - off] : 0;
        __syncthreads();
        incl[t] += add;
        __syncthreads();
    }
    if (t < NPG) {
        const int gstart = incl[t] - p;  // exclusive scan
        gs[t] = gstart;
        gsg[g * NPG + t] = gstart;
        gcg[g * NPG + t] = p;
        cur[t] = gstart * 4;
        nmask[g * NPG + t] = 1.0f;
        const float dv = rsqrtf(1.0f + (float)d);
        dinv[g * NPG + t] = dv;
        sc[g * NPG + t] = dv;
    }
    __syncthreads();
    for (int e = t; e < EPG; e += 512) {
        int dl = dst[g * EPG + e] - g * NPG;
        int pos = atomicAdd(&cur[dl], 1);
        slg[g * SLP + pos] = (unsigned short)(src[g * EPG + e] - g * NPG);
    }
    __syncthreads();
    if (t < NPG) {
        const int end = (gs[t] + p) * 4;
        for (int i = cur[t]; i < end; i++) slg[g * SLP + i] = (unsigned short)NPG;
    }
}

// --------------------------------------------------------------------- GEMM
// H = X @ W, register-tiled. MODE 0: plain store. MODE 2: relu(+b)*mask store
// + fused topk raw score (dot with p, shuffle tree). MODE 3: relu(+b)*mask,
// NO store, fused global max-pool into hp (values >= 0, hp pre-zeroed).
template<int IN, int OUT, int MODE>
__global__ __launch_bounds__(256) void gemm_kernel(
    const float* __restrict__ X, const float* __restrict__ W,
    const float* __restrict__ bias, const float* __restrict__ nmask,
    float* __restrict__ H, const float* __restrict__ p,
    float* __restrict__ score, float* __restrict__ hp) {
    __shared__ __align__(16) float sX[64 * IN];
    __shared__ unsigned smax[256];   // [2][128] for MODE 3
    const int row0 = blockIdx.x * 64;
    const int t = threadIdx.x;
    for (int i = t; i < 64 * IN / 4; i += 256)
        reinterpret_cast<float4*>(sX)[i] =
            reinterpret_cast<const float4*>(X + (size_t)row0 * IN)[i];
    if (MODE == 3) smax[t] = 0u;
    __syncthreads();
    constexpr int CG  = OUT / 4;   // 8,16,32
    constexpr int RG  = 256 / CG;  // 32,16,8
    constexpr int RPT = 64 / RG;   // 2,4,8
    const int c0 = (t % CG) * 4;
    const int r0 = (t / CG) * RPT;
    float acc[RPT][4];
#pragma unroll
    for (int r = 0; r < RPT; r++)
#pragma unroll
        for (int j = 0; j < 4; j++) acc[r][j] = 0.0f;
    for (int k4 = 0; k4 < IN / 4; k4++) {
        const float4 w0 = *reinterpret_cast<const float4*>(&W[(k4 * 4 + 0) * OUT + c0]);
        const float4 w1 = *reinterpret_cast<const float4*>(&W[(k4 * 4 + 1) * OUT + c0]);
        const float4 w2 = *reinterpret_cast<const float4*>(&W[(k4 * 4 + 2) * OUT + c0]);
        const float4 w3 = *reinterpret_cast<const float4*>(&W[(k4 * 4 + 3) * OUT + c0]);
#pragma unroll
        for (int r = 0; r < RPT; r++) {
            const float4 xv = *reinterpret_cast<const float4*>(&sX[(r0 + r) * IN + k4 * 4]);
            acc[r][0] += xv.x * w0.x + xv.y * w1.x + xv.z * w2.x + xv.w * w3.x;
            acc[r][1] += xv.x * w0.y + xv.y * w1.y + xv.z * w2.y + xv.w * w3.y;
            acc[r][2] += xv.x * w0.z + xv.y * w1.z + xv.z * w2.z + xv.w * w3.z;
            acc[r][3] += xv.x * w0.w + xv.y * w1.w + xv.z * w2.w + xv.w * w3.w;
        }
    }
    const int graph0 = row0 / 400;
    const int bnd = (graph0 + 1) * 400;   // first row of next graph (MODE 3)
    float ps[RPT];
    float cmax[4] = {0.f, 0.f, 0.f, 0.f};
#pragma unroll
    for (int r = 0; r < RPT; r++) {
        const int row = row0 + r0 + r;
        float4 v = make_float4(acc[r][0], acc[r][1], acc[r][2], acc[r][3]);
        if (MODE >= 2) {
            const float4 b4 = *reinterpret_cast<const float4*>(&bias[c0]);
            const float m = nmask[row];
            v.x = fmaxf(v.x + b4.x, 0.0f) * m;
            v.y = fmaxf(v.y + b4.y, 0.0f) * m;
            v.z = fmaxf(v.z + b4.z, 0.0f) * m;
            v.w = fmaxf(v.w + b4.w, 0.0f) * m;
        }
        if (MODE != 3) *reinterpret_cast<float4*>(&H[(size_t)row * OUT + c0]) = v;
        if (MODE == 2) {
            const float4 p4 = *reinterpret_cast<const float4*>(&p[c0]);
            ps[r] = v.x * p4.x + v.y * p4.y + v.z * p4.z + v.w * p4.w;
        }
        if (MODE == 3) {
            cmax[0] = fmaxf(cmax[0], v.x);
            cmax[1] = fmaxf(cmax[1], v.y);
            cmax[2] = fmaxf(cmax[2], v.z);
            cmax[3] = fmaxf(cmax[3], v.w);
        }
    }
    if (MODE == 2) {
#pragma unroll
        for (int r = 0; r < RPT; r++) {
#pragma unroll
            for (int off = 1; off < CG; off <<= 1) ps[r] += __shfl_xor(ps[r], off);
        }
        if ((t % CG) == 0) {
#pragma unroll
            for (int r = 0; r < RPT; r++) score[row0 + r0 + r] = ps[r];
        }
    }
    if (MODE == 3) {
        // thread's RPT=8 rows are contiguous & 400 % 8 == 0 -> single segment
        const int seg = ((row0 + r0) >= bnd) ? 1 : 0;
        atomicMax(&smax[seg * 128 + c0 + 0], __float_as_uint(cmax[0]));
        atomicMax(&smax[seg * 128 + c0 + 1], __float_as_uint(cmax[1]));
        atomicMax(&smax[seg * 128 + c0 + 2], __float_as_uint(cmax[2]));
        atomicMax(&smax[seg * 128 + c0 + 3], __float_as_uint(cmax[3]));
        __syncthreads();
        unsigned* hpu = reinterpret_cast<unsigned*>(hp);
        if (t < 128) atomicMax(&hpu[graph0 * 128 + t], smax[t]);
        const int graph1 = (row0 + 63) / 400;
        if (graph1 != graph0 && t < 128) atomicMax(&hpu[graph1 * 128 + t], smax[128 + t]);
    }
}

// ---------------------------------------------------------------- aggregate
// out[n] = dinv[n] * (Hs[n] + sum_{e:dst=n} Hs[src_e]),  Hs = H * sc
// SCORE: also emit raw topk score (out . p) via 8-lane shuffle tree.
template<int OUT, int NCH, int NS, bool EPI, bool SCORE>
__global__ __launch_bounds__(512) void gcn_agg_kernel(
    const float* __restrict__ H, float* __restrict__ Y,
    const float* __restrict__ dinv, const float* __restrict__ sc,
    const float* __restrict__ bias, const float* __restrict__ p,
    float* __restrict__ score,
    const unsigned short* __restrict__ slg, const int* __restrict__ gsg,
    const int* __restrict__ gcg) {
    __shared__ __align__(16) float Hl[(NPG + 1) * 36];
    __shared__ float dinvl[NPG];
    __shared__ int gsl[NPG];
    __shared__ int gcl[NPG];
    __shared__ unsigned long long sl64[SLP / 4];
    const unsigned short* sl = reinterpret_cast<const unsigned short*>(sl64);
    const int b   = blockIdx.x;
    const int g   = b / (NCH * NS);
    const int rem = b % (NCH * NS);
    const int f0  = (rem / NS) * 32;
    const int n0  = (rem % NS) * (NPG / NS);
    const int t   = threadIdx.x;

    for (int i = t; i < NPG; i += 512) {
        dinvl[i] = dinv[g * NPG + i];
        gsl[i] = gsg[g * NPG + i];
        gcl[i] = gcg[g * NPG + i];
    }
    for (int i = t; i < SLP / 4; i += 512)
        sl64[i] = reinterpret_cast<const unsigned long long*>(slg + (size_t)g * SLP)[i];
    if (t < 36) Hl[NPG * 36 + t] = 0.0f;   // zero row for pads
    for (int i = t; i < NPG * 8; i += 512) {
        const int n = i >> 3, q = i & 7;
        const float s = sc[g * NPG + n];
        float4 v = *reinterpret_cast<const float4*>(&H[(size_t)(g * NPG + n) * OUT + f0 + q * 4]);
        v.x *= s; v.y *= s; v.z *= s; v.w *= s;
        *reinterpret_cast<float4*>(&Hl[n * 36 + q * 4]) = v;
    }
    __syncthreads();

    const int wave = t >> 6, lane = t & 63;
    const int sub = lane >> 3, f4 = lane & 7;
    constexpr int NPB = NPG / NS;
    for (int n = n0 + wave * 8 + sub; n < n0 + NPB; n += 64) {
        const float di = dinvl[n];
        if (di == 0.0f) continue;   // inactive: consumer masks stale rows
        const int g0 = gsl[n], g1 = g0 + gcl[n];
        float4 acc = *reinterpret_cast<const float4*>(&Hl[n * 36 + f4 * 4]);  // self
        for (int gg = g0; gg < g1; ++gg) {
            const unsigned long long q = *reinterpret_cast<const unsigned long long*>(&sl[gg * 4]);
            const int s0 = (int)(q & 0xFFFF), s1 = (int)((q >> 16) & 0xFFFF);
            const int s2 = (int)((q >> 32) & 0xFFFF), s3 = (int)(q >> 48);
            const float4 a = *reinterpret_cast<const float4*>(&Hl[s0 * 36 + f4 * 4]);
            const float4 bb = *reinterpret_cast<const float4*>(&Hl[s1 * 36 + f4 * 4]);
            const float4 c = *reinterpret_cast<const float4*>(&Hl[s2 * 36 + f4 * 4]);
            const float4 dd = *reinterpret_cast<const float4*>(&Hl[s3 * 36 + f4 * 4]);
            acc.x += (a.x + bb.x) + (c.x + dd.x);
            acc.y += (a.y + bb.y) + (c.y + dd.y);
            acc.z += (a.z + bb.z) + (c.z + dd.z);
            acc.w += (a.w + bb.w) + (c.w + dd.w);
        }
        acc.x *= di; acc.y *= di; acc.z *= di; acc.w *= di;
        if (EPI) {
            const float4 b4 = *reinterpret_cast<const float4*>(&bias[f0 + f4 * 4]);
            acc.x = fmaxf(acc.x + b4.x, 0.0f);
            acc.y = fmaxf(acc.y + b4.y, 0.0f);
            acc.z = fmaxf(acc.z + b4.z, 0.0f);
            acc.w = fmaxf(acc.w + b4.w, 0.0f);
        }
        *reinterpret_cast<float4*>(&Y[(size_t)(g * NPG + n) * OUT + f0 + f4 * 4]) = acc;
        if (SCORE) {
            const float4 p4 = *reinterpret_cast<const float4*>(&p[f4 * 4]);
            float part = acc.x * p4.x + acc.y * p4.y + acc.z * p4.z + acc.w * p4.w;
            part += __shfl_xor(part, 1);
            part += __shfl_xor(part, 2);
            part += __shfl_xor(part, 4);
            if (f4 == 0) score[g * NPG + n] = part;
        }
    }
}

// ------------------------------------------------------------------- top-k
// Register bitonic sort: each thread owns one (val, idx). Stages j<64 via
// __shfl_xor (no barriers), j>=64 via LDS (6 stages, 12 barriers total).
// Comparator (val desc, idx asc) — exact lax.top_k set semantics.
template<int DIM>
__global__ __launch_bounds__(512) void topk_kernel(
    const float* __restrict__ score, float* __restrict__ nmask,
    float* __restrict__ dinv, float* __restrict__ sc,
    const float* __restrict__ p, int K,
    const unsigned short* __restrict__ slg, const int* __restrict__ gsg,
    const int* __restrict__ gcg) {
    __shared__ float sval[512];
    __shared__ int   sidx[512];
    __shared__ float sraw[NPG];
    __shared__ float nml[NPG + 1];
    __shared__ unsigned long long sl64[SLP / 4];
    __shared__ int gsl[NPG];
    __shared__ int gcl[NPG];
    __shared__ float spnorm;
    const unsigned short* sl = reinterpret_cast<const unsigned short*>(sl64);
    const int g = blockIdx.x;
    const int t = threadIdx.x;
    for (int i = t; i < SLP / 4; i += 512)
        sl64[i] = reinterpret_cast<const unsigned long long*>(slg + (size_t)g * SLP)[i];
    for (int i = t; i < NPG; i += 512) {
        gsl[i] = gsg[g * NPG + i];
        gcl[i] = gcg[g * NPG + i];
    }
    if (t == 0) {
        float s = 0.0f;
        for (int j = 0; j < DIM; j++) s += p[j] * p[j];
        spnorm = sqrtf(s);
    }
    float v = -INFINITY;
    int ix = t;
    if (t < NPG) {
        const float raw = score[g * NPG + t];
        sraw[t] = raw;
        v = (nmask[g * NPG + t] > 0.0f) ? raw : -INFINITY;
    }
    __syncthreads();
    for (int kk = 2; kk <= 512; kk <<= 1) {
        for (int j = kk >> 1; j > 0; j >>= 1) {
            float vb; int ib;
            if (j >= 64) {
                sval[t] = v; sidx[t] = ix;
                __syncthreads();
                vb = sval[t ^ j]; ib = sidx[t ^ j];
                __syncthreads();
            } else {
                vb = __shfl_xor(v, j, 64);
                ib = __shfl_xor(ix, j, 64);
            }
            const bool ownFirst = (v > vb) || (v == vb && ix < ib);
            const bool lower = (t & j) == 0;
            const bool desc = (t & kk) == 0;
            const bool keepOwn = lower ? (desc == ownFirst) : (desc != ownFirst);
            if (!keepOwn) { v = vb; ix = ib; }
        }
    }
    if (t <= NPG) nml[t] = 0.0f;
    __syncthreads();
    if (t < K) nml[ix] = 1.0f;   // thread t holds rank-t element
    __syncthreads();
    if (t < NPG) nmask[g * NPG + t] = nml[t];
    // next-layer dinv + sc from new mask
    for (int n = t; n < NPG; n += 512) {
        float dv = 0.0f;
        if (nml[n] > 0.0f) {
            float d = 1.0f;
            const int g0 = gsl[n], g1 = g0 + gcl[n];
            for (int gg = g0; gg < g1; ++gg) {
                const unsigned long long q = *reinterpret_cast<const unsigned long long*>(&sl[gg * 4]);
                d += nml[(int)(q & 0xFFFF)] + nml[(int)((q >> 16) & 0xFFFF)] +
                     nml[(int)((q >> 32) & 0xFFFF)] + nml[(int)(q >> 48)];
            }
            dv = rsqrtf(d);
        }
        dinv[g * NPG + n] = dv;
        sc[g * NPG + n] = (nml[n] > 0.0f) ? tanhf(sraw[n] / spnorm) * dv : 0.0f;
    }
}

// -------------------------------------------------------------------- head
// Single block, 512 threads, all 5 layers fused. LDS strides: mult-of-4
// (float4 reads) and !=0 mod 32 (bank spread). Bf stride OUT+1 for stats.
template<int IN, int OUT, int SA, int SO>
__device__ __forceinline__ void hlayer(float* A, float* Bf, float* Wl, float* smv,
                                       const float* __restrict__ W,
                                       const float* __restrict__ b,
                                       const float* __restrict__ ga,
                                       const float* __restrict__ be, int t) {
    for (int i = t; i < IN * OUT / 4; i += 512)
        reinterpret_cast<float4*>(Wl)[i] = reinterpret_cast<const float4*>(W)[i];
    __syncthreads();
    constexpr int RGS = 512 / OUT;   // row groups
    constexpr int RPT = 128 / RGS;   // rows per thread
    constexpr int SB  = OUT + 1;
    const int c = t % OUT, rg = t / OUT;
    const int rbase = rg * RPT;
    float acc[RPT];
#pragma unroll
    for (int k = 0; k < RPT; k++) acc[k] = 0.0f;
    for (int j4 = 0; j4 < IN / 4; j4++) {
        const float w0 = Wl[(j4 * 4 + 0) * OUT + c];
        const float w1 = Wl[(j4 * 4 + 1) * OUT + c];
        const float w2 = Wl[(j4 * 4 + 2) * OUT + c];
        const float w3 = Wl[(j4 * 4 + 3) * OUT + c];
#pragma unroll
        for (int k = 0; k < RPT; k++) {
            const float4 a = *reinterpret_cast<const float4*>(&A[(rbase + k) * SA + j4 * 4]);
            acc[k] += a.x * w0 + a.y * w1 + a.z * w2 + a.w * w3;
        }
    }
    const float bias = b[c];
#pragma unroll
    for (int k = 0; k < RPT; k++) Bf[(rbase + k) * SB + c] = acc[k] + bias;
    __syncthreads();
    if (t < OUT) {
        float s1 = 0.0f, s2 = 0.0f;
        for (int r = 0; r < 128; r++) {
            const float vv = Bf[r * SB + t];
            s1 += vv; s2 += vv * vv;
        }
        const float m = s1 * (1.0f / 128.0f);
        smv[t] = m;
        smv[64 + t] = s2 * (1.0f / 128.0f) - m * m;
    }
    __syncthreads();
    const float m = smv[c];
    const float scn = ga[c] * rsqrtf(smv[64 + c] + 1e-5f);
    const float bb = be[c];
#pragma unroll
    for (int k = 0; k < RPT; k++) {
        const float val = (acc[k] + bias - m) * scn + bb;
        A[(rbase + k) * SO + c] = fmaxf(val, 0.0f);
    }
    __syncthreads();
}

__global__ __launch_bounds__(512) void head_kernel(
    const float* __restrict__ HP,
    const float* __restrict__ Lw1, const float* __restrict__ Lb1,
    const float* __restrict__ Lw2, const float* __restrict__ Lb2,
    const float* __restrict__ Lw3, const float* __restrict__ Lb3,
    const float* __restrict__ Lw4, const float* __restrict__ Lb4,
    const float* __restrict__ Lw5, const float* __restrict__ Lb5,
    const float* __restrict__ g1, const float* __restrict__ be1,
    const float* __restrict__ g2, const float* __restrict__ be2,
    const float* __restrict__ g3, const float* __restrict__ be3,
    const float* __restrict__ g4, const float* __restrict__ be4,
    float* __restrict__ out) {
    __shared__ __align__(16) float A[128 * 132];
    __shared__ float Bf[128 * 65];
    __shared__ __align__(16) float Wl[128 * 64];
    __shared__ float smv[128];
    const int t = threadIdx.x;
    for (int i = t; i < 128 * 32; i += 512) {
        const int r = i >> 5, q = i & 31;
        reinterpret_cast<float4*>(&A[r * 132])[q] =
            reinterpret_cast<const float4*>(&HP[r * 128])[q];
    }
    __syncthreads();
    hlayer<128, 64, 132, 68>(A, Bf, Wl, smv, Lw1, Lb1, g1, be1, t);
    hlayer<64, 64, 68, 68>(A, Bf, Wl, smv, Lw2, Lb2, g2, be2, t);
    hlayer<64, 32, 68, 36>(A, Bf, Wl, smv, Lw3, Lb3, g3, be3, t);
    hlayer<32, 16, 36, 20>(A, Bf, Wl, smv, Lw4, Lb4, g4, be4, t);
    if (t < 128) {
        float acc = Lb5[0];
#pragma unroll
        for (int j = 0; j < 16; j++) acc += A[t * 20 + j] * Lw5[j];
        out[t] = acc;
    }
}

// ------------------------------------------------------------------ driver
extern "C" void kernel_launch(void* const* d_in, const int* in_sizes, int n_in,
                              void* d_out, int out_size, void* d_ws, size_t ws_size,
                              hipStream_t stream) {
    (void)in_sizes; (void)n_in; (void)out_size; (void)ws_size;
    const float* x   = (const float*)d_in[0];
    const int*   ei  = (const int*)d_in[1];
    const float* W1  = (const float*)d_in[3];  const float* b1  = (const float*)d_in[4];
    const float* W2  = (const float*)d_in[5];  const float* b2  = (const float*)d_in[6];
    const float* W3  = (const float*)d_in[7];  const float* b3  = (const float*)d_in[8];
    const float* W4  = (const float*)d_in[9];  const float* b4  = (const float*)d_in[10];
    const float* p1  = (const float*)d_in[11];
    const float* p2  = (const float*)d_in[12];
    const float* p3  = (const float*)d_in[13];
    const float* Lw1 = (const float*)d_in[14]; const float* Lb1 = (const float*)d_in[15];
    const float* Lw2 = (const float*)d_in[16]; const float* Lb2 = (const float*)d_in[17];
    const float* Lw3 = (const float*)d_in[18]; const float* Lb3 = (const float*)d_in[19];
    const float* Lw4 = (const float*)d_in[20]; const float* Lb4 = (const float*)d_in[21];
    const float* Lw5 = (const float*)d_in[22]; const float* Lb5 = (const float*)d_in[23];
    const float* g1  = (const float*)d_in[24]; const float* be1 = (const float*)d_in[25];
    const float* g2  = (const float*)d_in[26]; const float* be2 = (const float*)d_in[27];
    const float* g3  = (const float*)d_in[28]; const float* be3 = (const float*)d_in[29];
    const float* g4  = (const float*)d_in[30]; const float* be4 = (const float*)d_in[31];

    const int* src = ei;
    const int* dst = ei + NEDGES;

    float* ws    = (float*)d_ws;
    float* hb    = ws;                           // NNODES*128
    float* x0    = hb + (size_t)NNODES * 128;    // NNODES*128
    float* x1    = x0 + (size_t)NNODES * 128;    // NNODES*128
    float* nmask = x1 + (size_t)NNODES * 128;    // NNODES
    float* dinv  = nmask + NNODES;               // NNODES
    float* sc    = dinv + NNODES;                // NNODES
    float* scoreb= sc + NNODES;                  // NNODES
    float* hp    = scoreb + NNODES;              // 128*128
    unsigned short* slg = (unsigned short*)(hp + 128 * 128); // BGRAPHS*SLP u16
    int* gsg = (int*)(slg + (size_t)BGRAPHS * SLP);          // BGRAPHS*NPG
    int* gcg = gsg + (size_t)BGRAPHS * NPG;                  // BGRAPHS*NPG

    csr_build_kernel<<<BGRAPHS, 512, 0, stream>>>(src, dst, slg, gsg, gcg, nmask, dinv, sc, hp);

    // conv1 (64->32): gemm, then agg with fused bias+relu+score
    gemm_kernel<64, 32, 0><<<NNODES / 64, 256, 0, stream>>>(x, W1, nullptr, nullptr, hb, nullptr, nullptr, nullptr);
    gcn_agg_kernel<32, 1, 2, true, true><<<BGRAPHS * 2, 512, 0, stream>>>(hb, x0, dinv, sc, b1, p1, scoreb, slg, gsg, gcg);
    topk_kernel<32><<<BGRAPHS, 512, 0, stream>>>(scoreb, nmask, dinv, sc, p1, 360, slg, gsg, gcg);

    // conv2 (32->64): agg first (pool scale folded into sc), gemm w/ epilogue+score
    gcn_agg_kernel<32, 1, 2, false, false><<<BGRAPHS * 2, 512, 0, stream>>>(x0, hb, dinv, sc, nullptr, nullptr, nullptr, slg, gsg, gcg);
    gemm_kernel<32, 64, 2><<<NNODES / 64, 256, 0, stream>>>(hb, W2, b2, nmask, x1, p2, scoreb, nullptr);
    topk_kernel<64><<<BGRAPHS, 512, 0, stream>>>(scoreb, nmask, dinv, sc, p2, 324, slg, gsg, gcg);

    // conv3 (64->128): agg first, gemm w/ epilogue+score
    gcn_agg_kernel<64, 2, 2, false, false><<<BGRAPHS * 4, 512, 0, stream>>>(x1, hb, dinv, sc, nullptr, nullptr, nullptr, slg, gsg, gcg);
    gemm_kernel<64, 128, 2><<<NNODES / 64, 256, 0, stream>>>(hb, W3, b3, nmask, x0, p3, scoreb, nullptr);
    topk_kernel<128><<<BGRAPHS, 512, 0, stream>>>(scoreb, nmask, dinv, sc, p3, 292, slg, gsg, gcg);

    // conv4 (128->128): agg first, gemm with fused max-pool (no store)
    gcn_agg_kernel<128, 4, 1, false, false><<<BGRAPHS * 4, 512, 0, stream>>>(x0, hb, dinv, sc, nullptr, nullptr, nullptr, slg, gsg, gcg);
    gemm_kernel<128, 128, 3><<<NNODES / 64, 256, 0, stream>>>(hb, W4, b4, nmask, x1, nullptr, nullptr, hp);

    head_kernel<<<1, 512, 0, stream>>>(hp,
        Lw1, Lb1, Lw2, Lb2, Lw3, Lb3, Lw4, Lb4, Lw5, Lb5,
        g1, be1, g2, be2, g3, be3, g4, be4, (float*)d_out);
}

// Round 8
// 204.919 us; speedup vs baseline: 1.0482x; 1.0482x over previous
//
#include <hip/hip_runtime.h>
#include <math.h>

#define NNODES 51200
#define BGRAPHS 128
#define NPG 400
#define NEDGES 819200
#define EPG 6400    // edges per graph
#define SLP 7680    // padded src-list stride per graph (u16 entries, 1920 groups)

// ---------------- CSR build (padded 4-edge groups) ----------------
__global__ __launch_bounds__(512) void csr_build_kernel(
    const int* __restrict__ src, const int* __restrict__ dst,
    unsigned short* __restrict__ slg, int* __restrict__ gsg, int* __restrict__ gcg,
    float* __restrict__ nmask, float* __restrict__ dinv, float* __restrict__ sc,
    float* __restrict__ hp) {
    __shared__ int deg[NPG];
    __shared__ int incl[512];
    __shared__ int gs[NPG];
    __shared__ int cur[NPG];
    const int g = blockIdx.x, t = threadIdx.x;
    for (int i = t; i < NPG; i += 512) deg[i] = 0;
    if (t < 128) hp[g * 128 + t] = 0.0f;   // zero-init for gemm4's fused maxpool
    __syncthreads();
    for (int e = t; e < EPG; e += 512)
        atomicAdd(&deg[dst[g * EPG + e] - g * NPG], 1);
    __syncthreads();
    const int d = (t < NPG) ? deg[t] : 0;
    const int p = (d + 3) >> 2;   // padded group count
    incl[t] = p;
    __syncthreads();
    for (int off = 1; off < 512; off <<= 1) {
        int add = (t >= off) ? incl[t - off] : 0;
        __syncthreads();
        incl[t] += add;
        __syncthreads();
    }
    if (t < NPG) {
        const int gstart = incl[t] - p;  // exclusive scan
        gs[t] = gstart;
        gsg[g * NPG + t] = gstart;
        gcg[g * NPG + t] = p;
        cur[t] = gstart * 4;
        nmask[g * NPG + t] = 1.0f;
        const float dv = rsqrtf(1.0f + (float)d);
        dinv[g * NPG + t] = dv;
        sc[g * NPG + t] = dv;
    }
    __syncthreads();
    for (int e = t; e < EPG; e += 512) {
        int dl = dst[g * EPG + e] - g * NPG;
        int pos = atomicAdd(&cur[dl], 1);
        slg[g * SLP + pos] = (unsigned short)(src[g * EPG + e] - g * NPG);
    }
    __syncthreads();
    if (t < NPG) {
        const int end = (gs[t] + p) * 4;
        for (int i = cur[t]; i < end; i++) slg[g * SLP + i] = (unsigned short)NPG;
    }
}

// --------------------------------------------------------------------- GEMM
// H = X @ W, register-tiled. MODE 0: plain store. MODE 2: relu(+b)*mask store
// + fused topk raw score (dot with p, shuffle tree). MODE 3: relu(+b)*mask,
// NO store, fused global max-pool into hp (values >= 0, hp pre-zeroed).
template<int IN, int OUT, int MODE>
__global__ __launch_bounds__(256) void gemm_kernel(
    const float* __restrict__ X, const float* __restrict__ W,
    const float* __restrict__ bias, const float* __restrict__ nmask,
    float* __restrict__ H, const float* __restrict__ p,
    float* __restrict__ score, float* __restrict__ hp) {
    __shared__ __align__(16) float sX[64 * IN];
    __shared__ unsigned smax[256];   // [2][128] for MODE 3
    const int row0 = blockIdx.x * 64;
    const int t = threadIdx.x;
    for (int i = t; i < 64 * IN / 4; i += 256)
        reinterpret_cast<float4*>(sX)[i] =
            reinterpret_cast<const float4*>(X + (size_t)row0 * IN)[i];
    if (MODE == 3) smax[t] = 0u;
    __syncthreads();
    constexpr int CG  = OUT / 4;   // 8,16,32
    constexpr int RG  = 256 / CG;  // 32,16,8
    constexpr int RPT = 64 / RG;   // 2,4,8
    const int c0 = (t % CG) * 4;
    const int r0 = (t / CG) * RPT;
    float acc[RPT][4];
#pragma unroll
    for (int r = 0; r < RPT; r++)
#pragma unroll
        for (int j = 0; j < 4; j++) acc[r][j] = 0.0f;
    for (int k4 = 0; k4 < IN / 4; k4++) {
        const float4 w0 = *reinterpret_cast<const float4*>(&W[(k4 * 4 + 0) * OUT + c0]);
        const float4 w1 = *reinterpret_cast<const float4*>(&W[(k4 * 4 + 1) * OUT + c0]);
        const float4 w2 = *reinterpret_cast<const float4*>(&W[(k4 * 4 + 2) * OUT + c0]);
        const float4 w3 = *reinterpret_cast<const float4*>(&W[(k4 * 4 + 3) * OUT + c0]);
#pragma unroll
        for (int r = 0; r < RPT; r++) {
            const float4 xv = *reinterpret_cast<const float4*>(&sX[(r0 + r) * IN + k4 * 4]);
            acc[r][0] += xv.x * w0.x + xv.y * w1.x + xv.z * w2.x + xv.w * w3.x;
            acc[r][1] += xv.x * w0.y + xv.y * w1.y + xv.z * w2.y + xv.w * w3.y;
            acc[r][2] += xv.x * w0.z + xv.y * w1.z + xv.z * w2.z + xv.w * w3.z;
            acc[r][3] += xv.x * w0.w + xv.y * w1.w + xv.z * w2.w + xv.w * w3.w;
        }
    }
    const int graph0 = row0 / 400;
    const int bnd = (graph0 + 1) * 400;   // first row of next graph (MODE 3)
    float ps[RPT];
    float cmax[4] = {0.f, 0.f, 0.f, 0.f};
#pragma unroll
    for (int r = 0; r < RPT; r++) {
        const int row = row0 + r0 + r;
        float4 v = make_float4(acc[r][0], acc[r][1], acc[r][2], acc[r][3]);
        if (MODE >= 2) {
            const float4 b4 = *reinterpret_cast<const float4*>(&bias[c0]);
            const float m = nmask[row];
            v.x = fmaxf(v.x + b4.x, 0.0f) * m;
            v.y = fmaxf(v.y + b4.y, 0.0f) * m;
            v.z = fmaxf(v.z + b4.z, 0.0f) * m;
            v.w = fmaxf(v.w + b4.w, 0.0f) * m;
        }
        if (MODE != 3) *reinterpret_cast<float4*>(&H[(size_t)row * OUT + c0]) = v;
        if (MODE == 2) {
            const float4 p4 = *reinterpret_cast<const float4*>(&p[c0]);
            ps[r] = v.x * p4.x + v.y * p4.y + v.z * p4.z + v.w * p4.w;
        }
        if (MODE == 3) {
            cmax[0] = fmaxf(cmax[0], v.x);
            cmax[1] = fmaxf(cmax[1], v.y);
            cmax[2] = fmaxf(cmax[2], v.z);
            cmax[3] = fmaxf(cmax[3], v.w);
        }
    }
    if (MODE == 2) {
#pragma unroll
        for (int r = 0; r < RPT; r++) {
#pragma unroll
            for (int off = 1; off < CG; off <<= 1) ps[r] += __shfl_xor(ps[r], off);
        }
        if ((t % CG) == 0) {
#pragma unroll
            for (int r = 0; r < RPT; r++) score[row0 + r0 + r] = ps[r];
        }
    }
    if (MODE == 3) {
        // thread's RPT=8 rows are contiguous & 400 % 8 == 0 -> single segment
        const int seg = ((row0 + r0) >= bnd) ? 1 : 0;
        atomicMax(&smax[seg * 128 + c0 + 0], __float_as_uint(cmax[0]));
        atomicMax(&smax[seg * 128 + c0 + 1], __float_as_uint(cmax[1]));
        atomicMax(&smax[seg * 128 + c0 + 2], __float_as_uint(cmax[2]));
        atomicMax(&smax[seg * 128 + c0 + 3], __float_as_uint(cmax[3]));
        __syncthreads();
        unsigned* hpu = reinterpret_cast<unsigned*>(hp);
        if (t < 128) atomicMax(&hpu[graph0 * 128 + t], smax[t]);
        const int graph1 = (row0 + 63) / 400;
        if (graph1 != graph0 && t < 128) atomicMax(&hpu[graph1 * 128 + t], smax[128 + t]);
    }
}

// ---------------------------------------------------------------- aggregate
// out[n] = dinv[n] * (Hs[n] + sum_{e:dst=n} Hs[src_e]),  Hs = H * sc
// SCORE: also emit raw topk score (out . p) via 8-lane shuffle tree.
template<int OUT, int NCH, int NS, bool EPI, bool SCORE>
__global__ __launch_bounds__(512) void gcn_agg_kernel(
    const float* __restrict__ H, float* __restrict__ Y,
    const float* __restrict__ dinv, const float* __restrict__ sc,
    const float* __restrict__ bias, const float* __restrict__ p,
    float* __restrict__ score,
    const unsigned short* __restrict__ slg, const int* __restrict__ gsg,
    const int* __restrict__ gcg) {
    __shared__ __align__(16) float Hl[(NPG + 1) * 36];
    __shared__ float dinvl[NPG];
    __shared__ int gsl[NPG];
    __shared__ int gcl[NPG];
    __shared__ unsigned long long sl64[SLP / 4];
    const unsigned short* sl = reinterpret_cast<const unsigned short*>(sl64);
    const int b   = blockIdx.x;
    const int g   = b / (NCH * NS);
    const int rem = b % (NCH * NS);
    const int f0  = (rem / NS) * 32;
    const int n0  = (rem % NS) * (NPG / NS);
    const int t   = threadIdx.x;

    for (int i = t; i < NPG; i += 512) {
        dinvl[i] = dinv[g * NPG + i];
        gsl[i] = gsg[g * NPG + i];
        gcl[i] = gcg[g * NPG + i];
    }
    for (int i = t; i < SLP / 4; i += 512)
        sl64[i] = reinterpret_cast<const unsigned long long*>(slg + (size_t)g * SLP)[i];
    if (t < 36) Hl[NPG * 36 + t] = 0.0f;   // zero row for pads
    for (int i = t; i < NPG * 8; i += 512) {
        const int n = i >> 3, q = i & 7;
        const float s = sc[g * NPG + n];
        float4 v = *reinterpret_cast<const float4*>(&H[(size_t)(g * NPG + n) * OUT + f0 + q * 4]);
        v.x *= s; v.y *= s; v.z *= s; v.w *= s;
        *reinterpret_cast<float4*>(&Hl[n * 36 + q * 4]) = v;
    }
    __syncthreads();

    const int wave = t >> 6, lane = t & 63;
    const int sub = lane >> 3, f4 = lane & 7;
    constexpr int NPB = NPG / NS;
    for (int n = n0 + wave * 8 + sub; n < n0 + NPB; n += 64) {
        const float di = dinvl[n];
        if (di == 0.0f) continue;   // inactive: consumer masks stale rows
        const int g0 = gsl[n], g1 = g0 + gcl[n];
        float4 acc = *reinterpret_cast<const float4*>(&Hl[n * 36 + f4 * 4]);  // self
        for (int gg = g0; gg < g1; ++gg) {
            const unsigned long long q = *reinterpret_cast<const unsigned long long*>(&sl[gg * 4]);
            const int s0 = (int)(q & 0xFFFF), s1 = (int)((q >> 16) & 0xFFFF);
            const int s2 = (int)((q >> 32) & 0xFFFF), s3 = (int)(q >> 48);
            const float4 a = *reinterpret_cast<const float4*>(&Hl[s0 * 36 + f4 * 4]);
            const float4 bb = *reinterpret_cast<const float4*>(&Hl[s1 * 36 + f4 * 4]);
            const float4 c = *reinterpret_cast<const float4*>(&Hl[s2 * 36 + f4 * 4]);
            const float4 dd = *reinterpret_cast<const float4*>(&Hl[s3 * 36 + f4 * 4]);
            acc.x += (a.x + bb.x) + (c.x + dd.x);
            acc.y += (a.y + bb.y) + (c.y + dd.y);
            acc.z += (a.z + bb.z) + (c.z + dd.z);
            acc.w += (a.w + bb.w) + (c.w + dd.w);
        }
        acc.x *= di; acc.y *= di; acc.z *= di; acc.w *= di;
        if (EPI) {
            const float4 b4 = *reinterpret_cast<const float4*>(&bias[f0 + f4 * 4]);
            acc.x = fmaxf(acc.x + b4.x, 0.0f);
            acc.y = fmaxf(acc.y + b4.y, 0.0f);
            acc.z = fmaxf(acc.z + b4.z, 0.0f);
            acc.w = fmaxf(acc.w + b4.w, 0.0f);
        }
        *reinterpret_cast<float4*>(&Y[(size_t)(g * NPG + n) * OUT + f0 + f4 * 4]) = acc;
        if (SCORE) {
            const float4 p4 = *reinterpret_cast<const float4*>(&p[f4 * 4]);
            float part = acc.x * p4.x + acc.y * p4.y + acc.z * p4.z + acc.w * p4.w;
            part += __shfl_xor(part, 1);
            part += __shfl_xor(part, 2);
            part += __shfl_xor(part, 4);
            if (f4 == 0) score[g * NPG + n] = part;
        }
    }
}

// ------------------------------------------------------------------- top-k
// Register bitonic sort: each thread owns one (val, idx). Stages j<64 via
// __shfl_xor (no barriers), j>=64 via LDS (6 stages, 12 barriers total).
// Comparator (val desc, idx asc) — exact lax.top_k set semantics.
template<int DIM>
__global__ __launch_bounds__(512) void topk_kernel(
    const float* __restrict__ score, float* __restrict__ nmask,
    float* __restrict__ dinv, float* __restrict__ sc,
    const float* __restrict__ p, int K,
    const unsigned short* __restrict__ slg, const int* __restrict__ gsg,
    const int* __restrict__ gcg) {
    __shared__ float sval[512];
    __shared__ int   sidx[512];
    __shared__ float sraw[NPG];
    __shared__ float nml[NPG + 1];
    __shared__ unsigned long long sl64[SLP / 4];
    __shared__ int gsl[NPG];
    __shared__ int gcl[NPG];
    __shared__ float spnorm;
    const unsigned short* sl = reinterpret_cast<const unsigned short*>(sl64);
    const int g = blockIdx.x;
    const int t = threadIdx.x;
    for (int i = t; i < SLP / 4; i += 512)
        sl64[i] = reinterpret_cast<const unsigned long long*>(slg + (size_t)g * SLP)[i];
    for (int i = t; i < NPG; i += 512) {
        gsl[i] = gsg[g * NPG + i];
        gcl[i] = gcg[g * NPG + i];
    }
    if (t == 0) {
        float s = 0.0f;
        for (int j = 0; j < DIM; j++) s += p[j] * p[j];
        spnorm = sqrtf(s);
    }
    float v = -INFINITY;
    int ix = t;
    if (t < NPG) {
        const float raw = score[g * NPG + t];
        sraw[t] = raw;
        v = (nmask[g * NPG + t] > 0.0f) ? raw : -INFINITY;
    }
    __syncthreads();
    for (int kk = 2; kk <= 512; kk <<= 1) {
        for (int j = kk >> 1; j > 0; j >>= 1) {
            float vb; int ib;
            if (j >= 64) {
                sval[t] = v; sidx[t] = ix;
                __syncthreads();
                vb = sval[t ^ j]; ib = sidx[t ^ j];
                __syncthreads();
            } else {
                vb = __shfl_xor(v, j, 64);
                ib = __shfl_xor(ix, j, 64);
            }
            const bool ownFirst = (v > vb) || (v == vb && ix < ib);
            const bool lower = (t & j) == 0;
            const bool desc = (t & kk) == 0;
            const bool keepOwn = lower ? (desc == ownFirst) : (desc != ownFirst);
            if (!keepOwn) { v = vb; ix = ib; }
        }
    }
    if (t <= NPG) nml[t] = 0.0f;
    __syncthreads();
    if (t < K) nml[ix] = 1.0f;   // thread t holds rank-t element
    __syncthreads();
    if (t < NPG) nmask[g * NPG + t] = nml[t];
    // next-layer dinv + sc from new mask
    for (int n = t; n < NPG; n += 512) {
        float dv = 0.0f;
        if (nml[n] > 0.0f) {
            float d = 1.0f;
            const int g0 = gsl[n], g1 = g0 + gcl[n];
            for (int gg = g0; gg < g1; ++gg) {
                const unsigned long long q = *reinterpret_cast<const unsigned long long*>(&sl[gg * 4]);
                d += nml[(int)(q & 0xFFFF)] + nml[(int)((q >> 16) & 0xFFFF)] +
                     nml[(int)((q >> 32) & 0xFFFF)] + nml[(int)(q >> 48)];
            }
            dv = rsqrtf(d);
        }
        dinv[g * NPG + n] = dv;
        sc[g * NPG + n] = (nml[n] > 0.0f) ? tanhf(sraw[n] / spnorm) * dv : 0.0f;
    }
}

// -------------------------------------------------------------------- head
// One block per output column (BN stats are column-local). 128 threads = rows.
template<int IN, int OUT>
__global__ __launch_bounds__(128) void head_layer_kernel(
    const float* __restrict__ A, const float* __restrict__ W,
    const float* __restrict__ b, const float* __restrict__ ga,
    const float* __restrict__ be, float* __restrict__ Y) {
    __shared__ float Al[128 * (IN + 1)];
    __shared__ float red[4];
    const int c = blockIdx.x, t = threadIdx.x;
    for (int i = t; i < 128 * IN; i += 128)
        Al[(i / IN) * (IN + 1) + (i % IN)] = A[i];
    __syncthreads();
    float acc = b[c];
#pragma unroll
    for (int j = 0; j < IN; j++) acc += Al[t * (IN + 1) + j] * W[j * OUT + c];
    float s1 = acc, s2 = acc * acc;
    for (int o = 32; o > 0; o >>= 1) {
        s1 += __shfl_down(s1, o, 64);
        s2 += __shfl_down(s2, o, 64);
    }
    if ((t & 63) == 0) { red[t >> 6] = s1; red[2 + (t >> 6)] = s2; }
    __syncthreads();
    const float S1 = red[0] + red[1], S2 = red[2] + red[3];
    const float m = S1 * (1.0f / 128.0f);
    const float var = S2 * (1.0f / 128.0f) - m * m;
    float val = ga[c] * (acc - m) * rsqrtf(var + 1e-5f) + be[c];
    Y[t * OUT + c] = fmaxf(val, 0.0f);
}

__global__ __launch_bounds__(128) void head_final_kernel(
    const float* __restrict__ A, const float* __restrict__ w,
    const float* __restrict__ b, float* __restrict__ out) {
    const int t = threadIdx.x; // 128
    float acc = b[0];
#pragma unroll
    for (int j = 0; j < 16; j++) acc += A[t * 16 + j] * w[j];
    out[t] = acc;
}

// ------------------------------------------------------------------ driver
extern "C" void kernel_launch(void* const* d_in, const int* in_sizes, int n_in,
                              void* d_out, int out_size, void* d_ws, size_t ws_size,
                              hipStream_t stream) {
    (void)in_sizes; (void)n_in; (void)out_size; (void)ws_size;
    const float* x   = (const float*)d_in[0];
    const int*   ei  = (const int*)d_in[1];
    const float* W1  = (const float*)d_in[3];  const float* b1  = (const float*)d_in[4];
    const float* W2  = (const float*)d_in[5];  const float* b2  = (const float*)d_in[6];
    const float* W3  = (const float*)d_in[7];  const float* b3  = (const float*)d_in[8];
    const float* W4  = (const float*)d_in[9];  const float* b4  = (const float*)d_in[10];
    const float* p1  = (const float*)d_in[11];
    const float* p2  = (const float*)d_in[12];
    const float* p3  = (const float*)d_in[13];
    const float* Lw1 = (const float*)d_in[14]; const float* Lb1 = (const float*)d_in[15];
    const float* Lw2 = (const float*)d_in[16]; const float* Lb2 = (const float*)d_in[17];
    const float* Lw3 = (const float*)d_in[18]; const float* Lb3 = (const float*)d_in[19];
    const float* Lw4 = (const float*)d_in[20]; const float* Lb4 = (const float*)d_in[21];
    const float* Lw5 = (const float*)d_in[22]; const float* Lb5 = (const float*)d_in[23];
    const float* g1  = (const float*)d_in[24]; const float* be1 = (const float*)d_in[25];
    const float* g2  = (const float*)d_in[26]; const float* be2 = (const float*)d_in[27];
    const float* g3  = (const float*)d_in[28]; const float* be3 = (const float*)d_in[29];
    const float* g4  = (const float*)d_in[30]; const float* be4 = (const float*)d_in[31];

    const int* src = ei;
    const int* dst = ei + NEDGES;

    float* ws    = (float*)d_ws;
    float* hb    = ws;                           // NNODES*128
    float* x0    = hb + (size_t)NNODES * 128;    // NNODES*128
    float* x1    = x0 + (size_t)NNODES * 128;    // NNODES*128
    float* nmask = x1 + (size_t)NNODES * 128;    // NNODES
    float* dinv  = nmask + NNODES;               // NNODES
    float* sc    = dinv + NNODES;                // NNODES
    float* scoreb= sc + NNODES;                  // NNODES
    float* hp    = scoreb + NNODES;              // 128*128
    float* a1    = hp + 128 * 128;               // 128*64
    float* a2    = a1 + 128 * 64;                // 128*64
    float* a3    = a2 + 128 * 64;                // 128*32
    float* a4    = a3 + 128 * 32;                // 128*16
    unsigned short* slg = (unsigned short*)(a4 + 128 * 16); // BGRAPHS*SLP u16
    int* gsg = (int*)(slg + (size_t)BGRAPHS * SLP);          // BGRAPHS*NPG
    int* gcg = gsg + (size_t)BGRAPHS * NPG;                  // BGRAPHS*NPG

    csr_build_kernel<<<BGRAPHS, 512, 0, stream>>>(src, dst, slg, gsg, gcg, nmask, dinv, sc, hp);

    // conv1 (64->32): gemm, then agg with fused bias+relu+score
    gemm_kernel<64, 32, 0><<<NNODES / 64, 256, 0, stream>>>(x, W1, nullptr, nullptr, hb, nullptr, nullptr, nullptr);
    gcn_agg_kernel<32, 1, 2, true, true><<<BGRAPHS * 2, 512, 0, stream>>>(hb, x0, dinv, sc, b1, p1, scoreb, slg, gsg, gcg);
    topk_kernel<32><<<BGRAPHS, 512, 0, stream>>>(scoreb, nmask, dinv, sc, p1, 360, slg, gsg, gcg);

    // conv2 (32->64): agg first (pool scale folded into sc), gemm w/ epilogue+score
    gcn_agg_kernel<32, 1, 2, false, false><<<BGRAPHS * 2, 512, 0, stream>>>(x0, hb, dinv, sc, nullptr, nullptr, nullptr, slg, gsg, gcg);
    gemm_kernel<32, 64, 2><<<NNODES / 64, 256, 0, stream>>>(hb, W2, b2, nmask, x1, p2, scoreb, nullptr);
    topk_kernel<64><<<BGRAPHS, 512, 0, stream>>>(scoreb, nmask, dinv, sc, p2, 324, slg, gsg, gcg);

    // conv3 (64->128): agg first, gemm w/ epilogue+score
    gcn_agg_kernel<64, 2, 2, false, false><<<BGRAPHS * 4, 512, 0, stream>>>(x1, hb, dinv, sc, nullptr, nullptr, nullptr, slg, gsg, gcg);
    gemm_kernel<64, 128, 2><<<NNODES / 64, 256, 0, stream>>>(hb, W3, b3, nmask, x0, p3, scoreb, nullptr);
    topk_kernel<128><<<BGRAPHS, 512, 0, stream>>>(scoreb, nmask, dinv, sc, p3, 292, slg, gsg, gcg);

    // conv4 (128->128): agg first, gemm with fused max-pool (no store)
    gcn_agg_kernel<128, 4, 1, false, false><<<BGRAPHS * 4, 512, 0, stream>>>(x0, hb, dinv, sc, nullptr, nullptr, nullptr, slg, gsg, gcg);
    gemm_kernel<128, 128, 3><<<NNODES / 64, 256, 0, stream>>>(hb, W4, b4, nmask, x1, nullptr, nullptr, hp);

    head_layer_kernel<128, 64><<<64, 128, 0, stream>>>(hp, Lw1, Lb1, g1, be1, a1);
    head_layer_kernel<64, 64><<<64, 128, 0, stream>>>(a1, Lw2, Lb2, g2, be2, a2);
    head_layer_kernel<64, 32><<<32, 128, 0, stream>>>(a2, Lw3, Lb3, g3, be3, a3);
    head_layer_kernel<32, 16><<<16, 128, 0, stream>>>(a3, Lw4, Lb4, g4, be4, a4);
    head_final_kernel<<<1, 128, 0, stream>>>(a4, Lw5, Lb5, (float*)d_out);
}